// Round 12
// baseline (232.353 us; speedup 1.0000x reference)
//
#include <hip/hip_runtime.h>
#include <hip/hip_bf16.h>

#define Bq 2
#define Sq 2048
#define Hq 16
#define CHUNK 64
#define NC 32

typedef __attribute__((ext_vector_type(8))) short short8;  // 8 bf16
typedef __attribute__((ext_vector_type(4))) float f32x4;
typedef unsigned short ushort_t;
typedef unsigned int uint_t;

// ws map: wsM [0, 8388608)        : 1024 M tiles, bf16 linear [dv][dk], 8KB
//         wsV [8388608, 16777216) : 1024 V^T swizzled bf16 tiles, 8KB
// Scan counters (32 uints) live in the first 128B of d_out: memset per call,
// fully overwritten by attn_out_kernel afterwards.

__device__ inline short f2b(float f) {
  __hip_bfloat16 h = __float2bfloat16(f);
  return *reinterpret_cast<short*>(&h);
}
__device__ inline float b2f_lo(uint_t u) {
  union { uint_t u; float f; } x{u << 16};
  return x.f;
}
__device__ inline float b2f_hi(uint_t u) {
  union { uint_t u; float f; } x{u & 0xffff0000u};
  return x.f;
}
__device__ inline uint_t packbf(float lo, float hi) {
  return ((uint_t)(ushort_t)f2b(hi) << 16) | (uint_t)(ushort_t)f2b(lo);
}
// XOR-swizzled element index for a 64x64 bf16 tile (128B rows, 16B slots).
__device__ inline int swz(int row, int col) {
  return (row << 6) + ((((col >> 3) ^ (row & 7))) << 3) + (col & 7);
}

// ---------------------------------------------------------------------------
// Kernel A+B: round-6 kv_chunk body, then the LAST-finishing block of each bh
// (atomicAdd ticket, no spinning anywhere) performs that bh's exclusive
// chunk-prefix scan of wsM in-place (L2-warm, ~256KB r/w).
// ---------------------------------------------------------------------------
__global__ __launch_bounds__(256) void kv_chunk_scan_kernel(
    const float* __restrict__ qk, const float* __restrict__ v,
    ushort_t* __restrict__ wsM, ushort_t* __restrict__ wsV,
    uint_t* __restrict__ cnt) {
  const int u = blockIdx.x;
  const int c = u & 31, h = (u >> 5) & 15, b = u >> 9;
  const int bh = u >> 5;
  const int t0 = c * CHUNK;
  const int tid = threadIdx.x;
  __shared__ short ktS[4096];   // K^T[dk][s], swizzled
  __shared__ short vtS[4096];   // V^T[dv][s], swizzled

  const int x = tid & 63, seg = tid >> 6;
  for (int e = 0; e < 2; ++e) {
    const int s0 = seg * 16 + e * 8;
    short8 kb, vb;
#pragma unroll
    for (int j = 0; j < 8; ++j) {
      const size_t t = (size_t)(b * Sq + t0 + s0 + j);
      kb[j] = f2b(qk[((t * 2 + 1) * Hq + h) * 64 + x]);   // coalesced col read
      vb[j] = f2b(v[(t * Hq + h) * 64 + x]);
    }
    *(short8*)&ktS[swz(x, s0)] = kb;
    *(short8*)&vtS[swz(x, s0)] = vb;
  }
  __syncthreads();

  const int w = tid >> 6, lane = tid & 63, g = lane >> 4, r16 = lane & 15;
  short8 vf[2];
#pragma unroll
  for (int kk = 0; kk < 2; ++kk)
    vf[kk] = *(const short8*)&vtS[swz(16 * w + r16, kk * 32 + 8 * g)];

  // Dump swizzled V^T image (linear 16B stores).
  {
    ushort_t* dvp = wsV + ((size_t)u << 12);
    short8 a0 = *(const short8*)&vtS[tid * 16];
    short8 a1 = *(const short8*)&vtS[tid * 16 + 8];
    *(short8*)(dvp + tid * 16) = a0;
    *(short8*)(dvp + tid * 16 + 8) = a1;
  }

  // Chunk-aggregate KV tile -> wsM (linear [dv][dk] bf16).
  ushort_t* dst = wsM + ((size_t)u << 12);
#pragma unroll
  for (int j = 0; j < 4; ++j) {
    f32x4 acc = {0.f, 0.f, 0.f, 0.f};
#pragma unroll
    for (int kk = 0; kk < 2; ++kk) {
      short8 kf = *(const short8*)&ktS[swz(16 * j + r16, kk * 32 + 8 * g)];
      acc = __builtin_amdgcn_mfma_f32_16x16x32_bf16(vf[kk], kf, acc, 0, 0, 0);
    }
#pragma unroll
    for (int reg = 0; reg < 4; ++reg)
      dst[(16 * w + 4 * g + reg) * 64 + 16 * j + r16] = (ushort_t)f2b(acc[reg]);
  }

  // ---- ticket: last-finishing block of this bh scans (NO spinning) ----
  __threadfence();
  __syncthreads();
  __shared__ int isLast;
  if (tid == 0) {
    uint_t old = __hip_atomic_fetch_add(&cnt[bh], 1u, __ATOMIC_ACQ_REL,
                                        __HIP_MEMORY_SCOPE_AGENT);
    isLast = (old == NC - 1);
  }
  __syncthreads();
  if (!isLast) return;

  // Exclusive chunk-prefix scan of this bh's 32 tiles (round-6 kernel-B math;
  // thread tid owns uints [tid*8, tid*8+8) of each 2048-uint tile).
  uint_t* base = (uint_t*)wsM + (size_t)bh * NC * 2048 + tid * 8;
  float r[16];
#pragma unroll
  for (int i = 0; i < 16; ++i) r[i] = 0.f;
  for (int cc = 0; cc < NC; ++cc) {
    uint_t* p = base + cc * 2048;
    uint4 x0 = *(const uint4*)p;
    uint4 x1 = *(const uint4*)(p + 4);
    uint4 s0, s1;
    s0.x = packbf(r[0], r[1]);   s0.y = packbf(r[2], r[3]);
    s0.z = packbf(r[4], r[5]);   s0.w = packbf(r[6], r[7]);
    s1.x = packbf(r[8], r[9]);   s1.y = packbf(r[10], r[11]);
    s1.z = packbf(r[12], r[13]); s1.w = packbf(r[14], r[15]);
    *(uint4*)p = s0;
    *(uint4*)(p + 4) = s1;
    r[0] += b2f_lo(x0.x);  r[1] += b2f_hi(x0.x);
    r[2] += b2f_lo(x0.y);  r[3] += b2f_hi(x0.y);
    r[4] += b2f_lo(x0.z);  r[5] += b2f_hi(x0.z);
    r[6] += b2f_lo(x0.w);  r[7] += b2f_hi(x0.w);
    r[8] += b2f_lo(x1.x);  r[9] += b2f_hi(x1.x);
    r[10] += b2f_lo(x1.y); r[11] += b2f_hi(x1.y);
    r[12] += b2f_lo(x1.z); r[13] += b2f_hi(x1.z);
    r[14] += b2f_lo(x1.w); r[15] += b2f_hi(x1.w);
  }
}

// ---------------------------------------------------------------------------
// Kernel C: round-6 attn_out verbatim (one memory phase, pinned loads).
// ---------------------------------------------------------------------------
__global__ __launch_bounds__(256) void attn_out_kernel(
    const float* __restrict__ qk, const float* __restrict__ nrm,
    const ushort_t* __restrict__ wsM, const ushort_t* __restrict__ wsV,
    float* __restrict__ out) {
  const int u = blockIdx.x;
  const int c = u & 31, h = (u >> 5) & 15, b = u >> 9;
  const int t0 = c * CHUNK;
  const int tid = threadIdx.x;
  const int w = tid >> 6, lane = tid & 63, g = lane >> 4, r16 = lane & 15;
  __shared__ short smS[4096];

  const ushort_t* mm = wsM + ((size_t)u << 12);
  const ushort_t* vt = wsV + ((size_t)u << 12);
  const int nk = (w >> 1) + 1;

  short8 mfr[4][2];
#pragma unroll
  for (int j = 0; j < 4; ++j)
#pragma unroll
    for (int kk = 0; kk < 2; ++kk)
      mfr[j][kk] = *(const short8*)(mm + (16 * j + r16) * 64 + kk * 32 + 8 * g);

  short8 vfr[4][2];
#pragma unroll
  for (int kk = 0; kk < 2; ++kk)
#pragma unroll
    for (int j = 0; j < 4; ++j) {
      if (kk < nk)
        vfr[j][kk] = *(const short8*)(vt + swz(16 * j + r16, kk * 32 + 8 * g));
      else
        vfr[j][kk] = short8{};
    }

  float4 kraw[4][4];
#pragma unroll
  for (int j = 0; j < 4; ++j) {
    const size_t s = (size_t)(b * Sq + t0 + 16 * j + r16);
    const float4* kp = (const float4*)(qk + ((s * 2 + 1) * Hq + h) * 64);
#pragma unroll
    for (int p2 = 0; p2 < 2; ++p2) {
      if (j <= w) {
        kraw[j][2 * p2]     = kp[8 * p2 + 2 * g];
        kraw[j][2 * p2 + 1] = kp[8 * p2 + 2 * g + 1];
      } else {
        kraw[j][2 * p2]     = make_float4(0.f, 0.f, 0.f, 0.f);
        kraw[j][2 * p2 + 1] = make_float4(0.f, 0.f, 0.f, 0.f);
      }
    }
  }

  float4 qraw[4];
  {
    const size_t t = (size_t)(b * Sq + t0 + 16 * w + r16);
    const float4* qp = (const float4*)(qk + ((t * 2 + 0) * Hq + h) * 64);
#pragma unroll
    for (int p2 = 0; p2 < 2; ++p2) {
      qraw[2 * p2]     = qp[8 * p2 + 2 * g];
      qraw[2 * p2 + 1] = qp[8 * p2 + 2 * g + 1];
    }
  }

  float gn[4];
#pragma unroll
  for (int reg = 0; reg < 4; ++reg)
    gn[reg] = nrm[((size_t)(b * Sq) + t0 + 16 * w + 4 * g + reg) * Hq + h];

  __builtin_amdgcn_sched_barrier(0);

  short8 qf[2];
#pragma unroll
  for (int kk = 0; kk < 2; ++kk) {
    float4 a = qraw[2 * kk], bb = qraw[2 * kk + 1];
    short8 qv;
    qv[0] = f2b(a.x);  qv[1] = f2b(a.y);  qv[2] = f2b(a.z);  qv[3] = f2b(a.w);
    qv[4] = f2b(bb.x); qv[5] = f2b(bb.y); qv[6] = f2b(bb.z); qv[7] = f2b(bb.w);
    qf[kk] = qv;
  }

#pragma unroll
  for (int j = 0; j < 4; ++j) {
    f32x4 sacc = {0.f, 0.f, 0.f, 0.f};
#pragma unroll
    for (int kk = 0; kk < 2; ++kk) {
      float4 a = kraw[j][2 * kk], bb = kraw[j][2 * kk + 1];
      short8 kf;
      kf[0] = f2b(a.x);  kf[1] = f2b(a.y);  kf[2] = f2b(a.z);  kf[3] = f2b(a.w);
      kf[4] = f2b(bb.x); kf[5] = f2b(bb.y); kf[6] = f2b(bb.z); kf[7] = f2b(bb.w);
      sacc = __builtin_amdgcn_mfma_f32_16x16x32_bf16(qf[kk], kf, sacc, 0, 0, 0);
    }
    const int scol = 16 * j + r16;
#pragma unroll
    for (int reg = 0; reg < 4; ++reg) {
      const int trow = 16 * w + 4 * g + reg;
      smS[swz(trow, scol)] = (scol <= trow) ? f2b(sacc[reg]) : (short)0;
    }
  }
  asm volatile("s_waitcnt lgkmcnt(0)" ::: "memory");
  __builtin_amdgcn_sched_barrier(0);

  short8 sf0 = *(const short8*)&smS[swz(16 * w + r16, 8 * g)];
  short8 sf1 = short8{};
  if (nk > 1)
    sf1 = *(const short8*)&smS[swz(16 * w + r16, 32 + 8 * g)];

  float gr[4];
#pragma unroll
  for (int reg = 0; reg < 4; ++reg) gr[reg] = __expf(-gn[reg]);

#pragma unroll
  for (int j = 0; j < 4; ++j) {
    f32x4 oacc = {0.f, 0.f, 0.f, 0.f};
    oacc = __builtin_amdgcn_mfma_f32_16x16x32_bf16(sf0, vfr[j][0], oacc, 0, 0, 0);
    oacc = __builtin_amdgcn_mfma_f32_16x16x32_bf16(sf1, vfr[j][1], oacc, 0, 0, 0);
    oacc = __builtin_amdgcn_mfma_f32_16x16x32_bf16(qf[0], mfr[j][0], oacc, 0, 0, 0);
    oacc = __builtin_amdgcn_mfma_f32_16x16x32_bf16(qf[1], mfr[j][1], oacc, 0, 0, 0);
    const int dvv = 16 * j + r16;
#pragma unroll
    for (int reg = 0; reg < 4; ++reg) {
      const int trow = 16 * w + 4 * g + reg;
      out[((size_t)(b * Sq + t0 + trow) * Hq + h) * 64 + dvv] = gr[reg] * oacc[reg];
    }
  }
}

extern "C" void kernel_launch(void* const* d_in, const int* in_sizes, int n_in,
                              void* d_out, int out_size, void* d_ws, size_t ws_size,
                              hipStream_t stream) {
  const float* qk = (const float*)d_in[0];
  const float* v  = (const float*)d_in[1];
  const float* nn = (const float*)d_in[2];
  float* out = (float*)d_out;
  ushort_t* wsM = (ushort_t*)d_ws;                 // 8.39MB
  ushort_t* wsV = wsM + ((size_t)1024 << 12);      // +8.39MB = 16.78MB total

  // Scan counters: first 128B of d_out (fully overwritten by attn_out later).
  uint_t* cnt = (uint_t*)d_out;
  hipMemsetAsync(d_out, 0, 32 * sizeof(uint_t), stream);

  kv_chunk_scan_kernel<<<1024, 256, 0, stream>>>(qk, v, wsM, wsV, cnt);
  attn_out_kernel<<<1024, 256, 0, stream>>>(qk, nn, wsM, wsV, out);
}

// Round 13
// 49.440 us; speedup vs baseline: 4.6997x; 4.6997x over previous
//
#include <hip/hip_runtime.h>
#include <hip/hip_bf16.h>

#define Bq 2
#define Sq 2048
#define Hq 16
#define CHUNK 64
#define NC 32

typedef __attribute__((ext_vector_type(8))) short short8;  // 8 bf16
typedef __attribute__((ext_vector_type(4))) float f32x4;
typedef unsigned short ushort_t;
typedef unsigned int uint_t;

// ws map: wsM [0, 8388608)        : 1024 M tiles, bf16 linear [dv][dk], 8KB
//         wsV [8388608, 16777216) : 1024 V^T swizzled bf16 tiles, 8KB

__device__ inline short f2b(float f) {
  __hip_bfloat16 h = __float2bfloat16(f);
  return *reinterpret_cast<short*>(&h);
}
// XOR-swizzled element index for a 64x64 bf16 tile (128B rows, 16B slots).
__device__ inline int swz(int row, int col) {
  return (row << 6) + ((((col >> 3) ^ (row & 7))) << 3) + (col & 7);
}

// ---------------------------------------------------------------------------
// Kernel A (round-6 verbatim): stage K^T/V^T swizzled, dump V^T image to wsV,
// chunk-aggregate KV tile -> wsM (linear [dv][dk] bf16).
// ---------------------------------------------------------------------------
__global__ __launch_bounds__(256) void kv_chunk_kernel(
    const float* __restrict__ qk, const float* __restrict__ v,
    ushort_t* __restrict__ wsM, ushort_t* __restrict__ wsV) {
  const int u = blockIdx.x;
  const int c = u & 31, h = (u >> 5) & 15, b = u >> 9;
  const int t0 = c * CHUNK;
  const int tid = threadIdx.x;
  __shared__ short ktS[4096];   // K^T[dk][s], swizzled
  __shared__ short vtS[4096];   // V^T[dv][s], swizzled

  const int x = tid & 63, seg = tid >> 6;
  for (int e = 0; e < 2; ++e) {
    const int s0 = seg * 16 + e * 8;
    short8 kb, vb;
#pragma unroll
    for (int j = 0; j < 8; ++j) {
      const size_t t = (size_t)(b * Sq + t0 + s0 + j);
      kb[j] = f2b(qk[((t * 2 + 1) * Hq + h) * 64 + x]);   // coalesced col read
      vb[j] = f2b(v[(t * Hq + h) * 64 + x]);
    }
    *(short8*)&ktS[swz(x, s0)] = kb;
    *(short8*)&vtS[swz(x, s0)] = vb;
  }
  __syncthreads();

  const int w = tid >> 6, lane = tid & 63, g = lane >> 4, r16 = lane & 15;
  short8 vf[2];
#pragma unroll
  for (int kk = 0; kk < 2; ++kk)
    vf[kk] = *(const short8*)&vtS[swz(16 * w + r16, kk * 32 + 8 * g)];

  // Dump swizzled V^T image (linear 16B stores).
  {
    ushort_t* dvp = wsV + ((size_t)u << 12);
    short8 a0 = *(const short8*)&vtS[tid * 16];
    short8 a1 = *(const short8*)&vtS[tid * 16 + 8];
    *(short8*)(dvp + tid * 16) = a0;
    *(short8*)(dvp + tid * 16 + 8) = a1;
  }

  ushort_t* dst = wsM + ((size_t)u << 12);
#pragma unroll
  for (int j = 0; j < 4; ++j) {
    f32x4 acc = {0.f, 0.f, 0.f, 0.f};
#pragma unroll
    for (int kk = 0; kk < 2; ++kk) {
      short8 kf = *(const short8*)&ktS[swz(16 * j + r16, kk * 32 + 8 * g)];
      acc = __builtin_amdgcn_mfma_f32_16x16x32_bf16(vf[kk], kf, acc, 0, 0, 0);
    }
#pragma unroll
    for (int reg = 0; reg < 4; ++reg)
      dst[(16 * w + 4 * g + reg) * 64 + 16 * j + r16] = (ushort_t)f2b(acc[reg]);
  }
}

// ---------------------------------------------------------------------------
// Kernel B (round-6 verbatim): exclusive chunk-prefix of wsM per (b,h);
// packed bf16x2, fp32 accum; all 32 loads issued up-front.
// ---------------------------------------------------------------------------
__global__ __launch_bounds__(256) void kv_scan_kernel(uint_t* __restrict__ kvw) {
  const int gi = blockIdx.x * 256 + threadIdx.x;  // 65536 threads
  const int bh = gi >> 11, e = gi & 2047;
  uint_t* p = kvw + (size_t)bh * NC * 2048 + e;
  uint_t xv[NC];
#pragma unroll
  for (int cc = 0; cc < NC; ++cc) xv[cc] = p[cc * 2048];
  float r0 = 0.f, r1 = 0.f;
#pragma unroll
  for (int cc = 0; cc < NC; ++cc) {
    float lo = __uint_as_float(xv[cc] << 16);
    float hi = __uint_as_float(xv[cc] & 0xffff0000u);
    p[cc * 2048] = ((uint_t)(ushort_t)f2b(r1) << 16) | (uint_t)(ushort_t)f2b(r0);
    r0 += lo;
    r1 += hi;
  }
}

// ---------------------------------------------------------------------------
// Kernel C: SINGLE-WAVE blocks (4096 x 64). Per-wave work and reads are
// byte-identical to round 6 (each wave already read the full M tile + its own
// Q/K/V^T fragments); splitting removes intra-block scheduling coupling and
// lifts the 4-blocks/CU grid ceiling to ~16. M-path MFMAs issue before the
// score->LDS->PV chain (independent work overlapping the bounce drain).
// ---------------------------------------------------------------------------
__global__ __launch_bounds__(64) void attn_out_kernel(
    const float* __restrict__ qk, const float* __restrict__ nrm,
    const ushort_t* __restrict__ wsM, const ushort_t* __restrict__ wsV,
    float* __restrict__ out) {
  const int bid = blockIdx.x;
  const int u = bid >> 2;          // chunk unit
  const int w = bid & 3;           // former wave id: rows [16w, 16w+16)
  const int c = u & 31, h = (u >> 5) & 15, b = u >> 9;
  const int t0 = c * CHUNK;
  const int lane = threadIdx.x;    // 0..63
  const int g = lane >> 4, r16 = lane & 15;
  __shared__ short smS[1024];      // 16 rows x 64 cols, swizzled (2KB)

  const ushort_t* mm = wsM + ((size_t)u << 12);
  const ushort_t* vt = wsV + ((size_t)u << 12);
  const int nk = (w >> 1) + 1;     // live s-tiles: 1,1,2,2

  // ---- issue all global loads ----
  short8 mfr[4][2];
#pragma unroll
  for (int j = 0; j < 4; ++j)
#pragma unroll
    for (int kk = 0; kk < 2; ++kk)
      mfr[j][kk] = *(const short8*)(mm + (16 * j + r16) * 64 + kk * 32 + 8 * g);

  short8 vfr[4][2];
#pragma unroll
  for (int kk = 0; kk < 2; ++kk)
#pragma unroll
    for (int j = 0; j < 4; ++j) {
      if (kk < nk)
        vfr[j][kk] = *(const short8*)(vt + swz(16 * j + r16, kk * 32 + 8 * g));
      else
        vfr[j][kk] = short8{};
    }

  float4 kraw[4][4];
#pragma unroll
  for (int j = 0; j < 4; ++j) {
    const size_t s = (size_t)(b * Sq + t0 + 16 * j + r16);
    const float4* kp = (const float4*)(qk + ((s * 2 + 1) * Hq + h) * 64);
#pragma unroll
    for (int p2 = 0; p2 < 2; ++p2) {
      if (j <= w) {   // block-uniform
        kraw[j][2 * p2]     = kp[8 * p2 + 2 * g];
        kraw[j][2 * p2 + 1] = kp[8 * p2 + 2 * g + 1];
      } else {
        kraw[j][2 * p2]     = make_float4(0.f, 0.f, 0.f, 0.f);
        kraw[j][2 * p2 + 1] = make_float4(0.f, 0.f, 0.f, 0.f);
      }
    }
  }

  float4 qraw[4];
  {
    const size_t t = (size_t)(b * Sq + t0 + 16 * w + r16);
    const float4* qp = (const float4*)(qk + ((t * 2 + 0) * Hq + h) * 64);
#pragma unroll
    for (int p2 = 0; p2 < 2; ++p2) {
      qraw[2 * p2]     = qp[8 * p2 + 2 * g];
      qraw[2 * p2 + 1] = qp[8 * p2 + 2 * g + 1];
    }
  }

  float gn[4];
#pragma unroll
  for (int reg = 0; reg < 4; ++reg)
    gn[reg] = nrm[((size_t)(b * Sq) + t0 + 16 * w + 4 * g + reg) * Hq + h];

  __builtin_amdgcn_sched_barrier(0);   // pin loads above compute

  // ---- Q fragments ----
  short8 qf[2];
#pragma unroll
  for (int kk = 0; kk < 2; ++kk) {
    float4 a = qraw[2 * kk], bb = qraw[2 * kk + 1];
    short8 qv;
    qv[0] = f2b(a.x);  qv[1] = f2b(a.y);  qv[2] = f2b(a.z);  qv[3] = f2b(a.w);
    qv[4] = f2b(bb.x); qv[5] = f2b(bb.y); qv[6] = f2b(bb.z); qv[7] = f2b(bb.w);
    qf[kk] = qv;
  }

  // ---- M-path first: oacc[j] = Q @ M_prev (independent of score chain) ----
  f32x4 oacc[4];
#pragma unroll
  for (int j = 0; j < 4; ++j) {
    oacc[j] = f32x4{0.f, 0.f, 0.f, 0.f};
    oacc[j] = __builtin_amdgcn_mfma_f32_16x16x32_bf16(qf[0], mfr[j][0], oacc[j], 0, 0, 0);
    oacc[j] = __builtin_amdgcn_mfma_f32_16x16x32_bf16(qf[1], mfr[j][1], oacc[j], 0, 0, 0);
  }

  // ---- scores -> masked bf16 -> private LDS (intra-wave bounce) ----
#pragma unroll
  for (int j = 0; j < 4; ++j) {
    f32x4 sacc = {0.f, 0.f, 0.f, 0.f};
#pragma unroll
    for (int kk = 0; kk < 2; ++kk) {
      float4 a = kraw[j][2 * kk], bb = kraw[j][2 * kk + 1];
      short8 kf;
      kf[0] = f2b(a.x);  kf[1] = f2b(a.y);  kf[2] = f2b(a.z);  kf[3] = f2b(a.w);
      kf[4] = f2b(bb.x); kf[5] = f2b(bb.y); kf[6] = f2b(bb.z); kf[7] = f2b(bb.w);
      sacc = __builtin_amdgcn_mfma_f32_16x16x32_bf16(qf[kk], kf, sacc, 0, 0, 0);
    }
    const int scol = 16 * j + r16;
#pragma unroll
    for (int reg = 0; reg < 4; ++reg) {
      const int trow = 16 * w + 4 * g + reg;       // global row for the mask
      smS[swz(4 * g + reg, scol)] = (scol <= trow) ? f2b(sacc[reg]) : (short)0;
    }
  }
  asm volatile("s_waitcnt lgkmcnt(0)" ::: "memory");
  __builtin_amdgcn_sched_barrier(0);

  short8 sf0 = *(const short8*)&smS[swz(r16, 8 * g)];
  short8 sf1 = short8{};
  if (nk > 1)
    sf1 = *(const short8*)&smS[swz(r16, 32 + 8 * g)];

  float gr[4];
#pragma unroll
  for (int reg = 0; reg < 4; ++reg) gr[reg] = __expf(-gn[reg]);

  // ---- PV accumulate + gate + store ----
#pragma unroll
  for (int j = 0; j < 4; ++j) {
    oacc[j] = __builtin_amdgcn_mfma_f32_16x16x32_bf16(sf0, vfr[j][0], oacc[j], 0, 0, 0);
    oacc[j] = __builtin_amdgcn_mfma_f32_16x16x32_bf16(sf1, vfr[j][1], oacc[j], 0, 0, 0);
    const int dvv = 16 * j + r16;
#pragma unroll
    for (int reg = 0; reg < 4; ++reg) {
      const int trow = 16 * w + 4 * g + reg;
      out[((size_t)(b * Sq + t0 + trow) * Hq + h) * 64 + dvv] = gr[reg] * oacc[j][reg];
    }
  }
}

extern "C" void kernel_launch(void* const* d_in, const int* in_sizes, int n_in,
                              void* d_out, int out_size, void* d_ws, size_t ws_size,
                              hipStream_t stream) {
  const float* qk = (const float*)d_in[0];
  const float* v  = (const float*)d_in[1];
  const float* nn = (const float*)d_in[2];
  float* out = (float*)d_out;
  ushort_t* wsM = (ushort_t*)d_ws;                 // 8.39MB
  ushort_t* wsV = wsM + ((size_t)1024 << 12);      // +8.39MB = 16.78MB total

  kv_chunk_kernel<<<1024, 256, 0, stream>>>(qk, v, wsM, wsV);
  kv_scan_kernel<<<256, 256, 0, stream>>>((uint_t*)wsM);
  attn_out_kernel<<<4096, 64, 0, stream>>>(qk, nn, wsM, wsV, out);
}

// Round 14
// 34.357 us; speedup vs baseline: 6.7630x; 1.4390x over previous
//
#include <hip/hip_runtime.h>
#include <hip/hip_bf16.h>

#define Bq 2
#define Sq 2048
#define Hq 16
#define CHUNK 64
#define NC 32

typedef __attribute__((ext_vector_type(8))) short short8;  // 8 bf16
typedef __attribute__((ext_vector_type(4))) float f32x4;
typedef unsigned short ushort_t;
typedef unsigned int uint_t;

// ws map: wsM [0, 8388608)        : 1024 M tiles, bf16 linear [dv][dk], 8KB
//         wsV [8388608, 16777216) : 1024 V^T swizzled bf16 tiles, 8KB

__device__ inline short f2b(float f) {
  __hip_bfloat16 h = __float2bfloat16(f);
  return *reinterpret_cast<short*>(&h);
}
// XOR-swizzled element index for a 64x64 bf16 tile (128B rows, 16B slots).
__device__ inline int swz(int row, int col) {
  return (row << 6) + ((((col >> 3) ^ (row & 7))) << 3) + (col & 7);
}

// ---------------------------------------------------------------------------
// Kernel A (round-6 verbatim): stage K^T/V^T swizzled, dump V^T image to wsV,
// chunk-aggregate KV tile -> wsM (linear [dv][dk] bf16).
// ---------------------------------------------------------------------------
__global__ __launch_bounds__(256) void kv_chunk_kernel(
    const float* __restrict__ qk, const float* __restrict__ v,
    ushort_t* __restrict__ wsM, ushort_t* __restrict__ wsV) {
  const int u = blockIdx.x;
  const int c = u & 31, h = (u >> 5) & 15, b = u >> 9;
  const int t0 = c * CHUNK;
  const int tid = threadIdx.x;
  __shared__ short ktS[4096];   // K^T[dk][s], swizzled
  __shared__ short vtS[4096];   // V^T[dv][s], swizzled

  const int x = tid & 63, seg = tid >> 6;
  for (int e = 0; e < 2; ++e) {
    const int s0 = seg * 16 + e * 8;
    short8 kb, vb;
#pragma unroll
    for (int j = 0; j < 8; ++j) {
      const size_t t = (size_t)(b * Sq + t0 + s0 + j);
      kb[j] = f2b(qk[((t * 2 + 1) * Hq + h) * 64 + x]);   // coalesced col read
      vb[j] = f2b(v[(t * Hq + h) * 64 + x]);
    }
    *(short8*)&ktS[swz(x, s0)] = kb;
    *(short8*)&vtS[swz(x, s0)] = vb;
  }
  __syncthreads();

  const int w = tid >> 6, lane = tid & 63, g = lane >> 4, r16 = lane & 15;
  short8 vf[2];
#pragma unroll
  for (int kk = 0; kk < 2; ++kk)
    vf[kk] = *(const short8*)&vtS[swz(16 * w + r16, kk * 32 + 8 * g)];

  // Dump swizzled V^T image (linear 16B stores).
  {
    ushort_t* dvp = wsV + ((size_t)u << 12);
    short8 a0 = *(const short8*)&vtS[tid * 16];
    short8 a1 = *(const short8*)&vtS[tid * 16 + 8];
    *(short8*)(dvp + tid * 16) = a0;
    *(short8*)(dvp + tid * 16 + 8) = a1;
  }

  ushort_t* dst = wsM + ((size_t)u << 12);
#pragma unroll
  for (int j = 0; j < 4; ++j) {
    f32x4 acc = {0.f, 0.f, 0.f, 0.f};
#pragma unroll
    for (int kk = 0; kk < 2; ++kk) {
      short8 kf = *(const short8*)&ktS[swz(16 * j + r16, kk * 32 + 8 * g)];
      acc = __builtin_amdgcn_mfma_f32_16x16x32_bf16(vf[kk], kf, acc, 0, 0, 0);
    }
#pragma unroll
    for (int reg = 0; reg < 4; ++reg)
      dst[(16 * w + 4 * g + reg) * 64 + 16 * j + r16] = (ushort_t)f2b(acc[reg]);
  }
}

// ---------------------------------------------------------------------------
// Kernel B (round-6 verbatim): exclusive chunk-prefix of wsM per (b,h);
// packed bf16x2, fp32 accum; all 32 loads issued up-front.
// ---------------------------------------------------------------------------
__global__ __launch_bounds__(256) void kv_scan_kernel(uint_t* __restrict__ kvw) {
  const int gi = blockIdx.x * 256 + threadIdx.x;  // 65536 threads
  const int bh = gi >> 11, e = gi & 2047;
  uint_t* p = kvw + (size_t)bh * NC * 2048 + e;
  uint_t xv[NC];
#pragma unroll
  for (int cc = 0; cc < NC; ++cc) xv[cc] = p[cc * 2048];
  float r0 = 0.f, r1 = 0.f;
#pragma unroll
  for (int cc = 0; cc < NC; ++cc) {
    float lo = __uint_as_float(xv[cc] << 16);
    float hi = __uint_as_float(xv[cc] & 0xffff0000u);
    p[cc * 2048] = ((uint_t)(ushort_t)f2b(r1) << 16) | (uint_t)(ushort_t)f2b(r0);
    r0 += lo;
    r1 += hi;
  }
}

// ---------------------------------------------------------------------------
// Kernel C: round-6 structure; ONE change: the 8 M-path MFMAs (Q @ M_prev)
// seed the output accumulators BEFORE the score chain, so the kraw-cvt burst
// and the LDS score bounce overlap matrix work instead of preceding it.
// ---------------------------------------------------------------------------
__global__ __launch_bounds__(256) void attn_out_kernel(
    const float* __restrict__ qk, const float* __restrict__ nrm,
    const ushort_t* __restrict__ wsM, const ushort_t* __restrict__ wsV,
    float* __restrict__ out) {
  const int u = blockIdx.x;
  const int c = u & 31, h = (u >> 5) & 15, b = u >> 9;
  const int t0 = c * CHUNK;
  const int tid = threadIdx.x;
  const int w = tid >> 6, lane = tid & 63, g = lane >> 4, r16 = lane & 15;
  __shared__ short smS[4096];

  const ushort_t* mm = wsM + ((size_t)u << 12);
  const ushort_t* vt = wsV + ((size_t)u << 12);
  const int nk = (w >> 1) + 1;

  // ---- issue ALL global loads ----
  short8 mfr[4][2];
#pragma unroll
  for (int j = 0; j < 4; ++j)
#pragma unroll
    for (int kk = 0; kk < 2; ++kk)
      mfr[j][kk] = *(const short8*)(mm + (16 * j + r16) * 64 + kk * 32 + 8 * g);

  short8 vfr[4][2];
#pragma unroll
  for (int kk = 0; kk < 2; ++kk)
#pragma unroll
    for (int j = 0; j < 4; ++j) {
      if (kk < nk)
        vfr[j][kk] = *(const short8*)(vt + swz(16 * j + r16, kk * 32 + 8 * g));
      else
        vfr[j][kk] = short8{};
    }

  float4 kraw[4][4];
#pragma unroll
  for (int j = 0; j < 4; ++j) {
    const size_t s = (size_t)(b * Sq + t0 + 16 * j + r16);
    const float4* kp = (const float4*)(qk + ((s * 2 + 1) * Hq + h) * 64);
#pragma unroll
    for (int p2 = 0; p2 < 2; ++p2) {
      if (j <= w) {
        kraw[j][2 * p2]     = kp[8 * p2 + 2 * g];
        kraw[j][2 * p2 + 1] = kp[8 * p2 + 2 * g + 1];
      } else {
        kraw[j][2 * p2]     = make_float4(0.f, 0.f, 0.f, 0.f);
        kraw[j][2 * p2 + 1] = make_float4(0.f, 0.f, 0.f, 0.f);
      }
    }
  }

  float4 qraw[4];
  {
    const size_t t = (size_t)(b * Sq + t0 + 16 * w + r16);
    const float4* qp = (const float4*)(qk + ((t * 2 + 0) * Hq + h) * 64);
#pragma unroll
    for (int p2 = 0; p2 < 2; ++p2) {
      qraw[2 * p2]     = qp[8 * p2 + 2 * g];
      qraw[2 * p2 + 1] = qp[8 * p2 + 2 * g + 1];
    }
  }

  float gn[4];
#pragma unroll
  for (int reg = 0; reg < 4; ++reg)
    gn[reg] = nrm[((size_t)(b * Sq) + t0 + 16 * w + 4 * g + reg) * Hq + h];

  __builtin_amdgcn_sched_barrier(0);   // pin loads above compute

  // ---- Q fragments ----
  short8 qf[2];
#pragma unroll
  for (int kk = 0; kk < 2; ++kk) {
    float4 a = qraw[2 * kk], bb = qraw[2 * kk + 1];
    short8 qv;
    qv[0] = f2b(a.x);  qv[1] = f2b(a.y);  qv[2] = f2b(a.z);  qv[3] = f2b(a.w);
    qv[4] = f2b(bb.x); qv[5] = f2b(bb.y); qv[6] = f2b(bb.z); qv[7] = f2b(bb.w);
    qf[kk] = qv;
  }

  // ---- M-path first: oacc[j] = Q @ M_prev (independent of score chain) ----
  f32x4 oacc[4];
#pragma unroll
  for (int j = 0; j < 4; ++j) {
    oacc[j] = f32x4{0.f, 0.f, 0.f, 0.f};
    oacc[j] = __builtin_amdgcn_mfma_f32_16x16x32_bf16(qf[0], mfr[j][0], oacc[j], 0, 0, 0);
    oacc[j] = __builtin_amdgcn_mfma_f32_16x16x32_bf16(qf[1], mfr[j][1], oacc[j], 0, 0, 0);
  }

  // ---- scores -> masked bf16 -> LDS bounce ----
#pragma unroll
  for (int j = 0; j < 4; ++j) {
    f32x4 sacc = {0.f, 0.f, 0.f, 0.f};
#pragma unroll
    for (int kk = 0; kk < 2; ++kk) {
      float4 a = kraw[j][2 * kk], bb = kraw[j][2 * kk + 1];
      short8 kf;
      kf[0] = f2b(a.x);  kf[1] = f2b(a.y);  kf[2] = f2b(a.z);  kf[3] = f2b(a.w);
      kf[4] = f2b(bb.x); kf[5] = f2b(bb.y); kf[6] = f2b(bb.z); kf[7] = f2b(bb.w);
      sacc = __builtin_amdgcn_mfma_f32_16x16x32_bf16(qf[kk], kf, sacc, 0, 0, 0);
    }
    const int scol = 16 * j + r16;
#pragma unroll
    for (int reg = 0; reg < 4; ++reg) {
      const int trow = 16 * w + 4 * g + reg;
      smS[swz(trow, scol)] = (scol <= trow) ? f2b(sacc[reg]) : (short)0;
    }
  }
  asm volatile("s_waitcnt lgkmcnt(0)" ::: "memory");
  __builtin_amdgcn_sched_barrier(0);

  short8 sf0 = *(const short8*)&smS[swz(16 * w + r16, 8 * g)];
  short8 sf1 = short8{};
  if (nk > 1)
    sf1 = *(const short8*)&smS[swz(16 * w + r16, 32 + 8 * g)];

  float gr[4];
#pragma unroll
  for (int reg = 0; reg < 4; ++reg) gr[reg] = __expf(-gn[reg]);

  // ---- PV accumulate + gate + store ----
#pragma unroll
  for (int j = 0; j < 4; ++j) {
    oacc[j] = __builtin_amdgcn_mfma_f32_16x16x32_bf16(sf0, vfr[j][0], oacc[j], 0, 0, 0);
    oacc[j] = __builtin_amdgcn_mfma_f32_16x16x32_bf16(sf1, vfr[j][1], oacc[j], 0, 0, 0);
    const int dvv = 16 * j + r16;
#pragma unroll
    for (int reg = 0; reg < 4; ++reg) {
      const int trow = 16 * w + 4 * g + reg;
      out[((size_t)(b * Sq + t0 + trow) * Hq + h) * 64 + dvv] = gr[reg] * oacc[j][reg];
    }
  }
}

extern "C" void kernel_launch(void* const* d_in, const int* in_sizes, int n_in,
                              void* d_out, int out_size, void* d_ws, size_t ws_size,
                              hipStream_t stream) {
  const float* qk = (const float*)d_in[0];
  const float* v  = (const float*)d_in[1];
  const float* nn = (const float*)d_in[2];
  float* out = (float*)d_out;
  ushort_t* wsM = (ushort_t*)d_ws;                 // 8.39MB
  ushort_t* wsV = wsM + ((size_t)1024 << 12);      // +8.39MB = 16.78MB total

  kv_chunk_kernel<<<1024, 256, 0, stream>>>(qk, v, wsM, wsV);
  kv_scan_kernel<<<256, 256, 0, stream>>>((uint_t*)wsM);
  attn_out_kernel<<<1024, 256, 0, stream>>>(qk, nn, wsM, wsV, out);
}